// Round 9
// baseline (458.433 us; speedup 1.0000x reference)
//
#include <hip/hip_runtime.h>
#include <hip/hip_bf16.h>
#include <math.h>

#define HD 1024
#define NCLS 10001

typedef short s16x8 __attribute__((ext_vector_type(8)));
typedef unsigned short u16x8 __attribute__((ext_vector_type(8)));
typedef unsigned short u16x4 __attribute__((ext_vector_type(4)));
typedef float f32x4 __attribute__((ext_vector_type(4)));
#define MFMA16(a_, b_, c_) __builtin_amdgcn_mfma_f32_16x16x32_bf16((a_), (b_), (c_), 0, 0, 0)

__device__ __forceinline__ float sigf(float x){ return 1.f/(1.f+__expf(-x)); }
__device__ __forceinline__ float tanhfast(float x){
  x = fminf(fmaxf(x,-10.f),10.f);
  float e2 = __expf(2.f*x);
  return (e2-1.f)/(e2+1.f);
}
__device__ __forceinline__ unsigned short f2bf(float f){
  unsigned int u = __float_as_uint(f);
  u += 0x7FFF + ((u >> 16) & 1);          // round-to-nearest-even
  return (unsigned short)(u >> 16);
}
__device__ __forceinline__ float bf2f(unsigned short u){
  return __uint_as_float(((unsigned)u) << 16);
}
__device__ __forceinline__ u16x8 pack8(float4 a, float4 b){
  u16x8 r;
  r[0]=f2bf(a.x); r[1]=f2bf(a.y); r[2]=f2bf(a.z); r[3]=f2bf(a.w);
  r[4]=f2bf(b.x); r[5]=f2bf(b.y); r[6]=f2bf(b.z); r[7]=f2bf(b.w);
  return r;
}

// ---------------- fp32 -> bf16 bulk convert, 32 elems/thread (deep ILP), n % 32 == 0 ----------------
__global__ __launch_bounds__(256) void k_cvt32(const float* __restrict__ A, unsigned short* __restrict__ B, int n){
  int i = (blockIdx.x*256 + threadIdx.x)*32;
  if (i >= n) return;
  float4 a0 = *(const float4*)(A+i+ 0), b0 = *(const float4*)(A+i+ 4);
  float4 a1 = *(const float4*)(A+i+ 8), b1 = *(const float4*)(A+i+12);
  float4 a2 = *(const float4*)(A+i+16), b2 = *(const float4*)(A+i+20);
  float4 a3 = *(const float4*)(A+i+24), b3 = *(const float4*)(A+i+28);
  *(u16x8*)(B+i+ 0) = pack8(a0,b0);
  *(u16x8*)(B+i+ 8) = pack8(a1,b1);
  *(u16x8*)(B+i+16) = pack8(a2,b2);
  *(u16x8*)(B+i+24) = pack8(a3,b3);
}

// ---------------- split W_pre: cols [0,1024) -> Bpre[row][0:1024] (stride 1536); cols [1024,2048) -> Wc ----------------
__global__ __launch_bounds__(256) void k_cvtpre8(const float* __restrict__ Wpre,
                                                 unsigned short* __restrict__ Bpre, unsigned short* __restrict__ Wc){
  unsigned idx8 = (blockIdx.x*256 + threadIdx.x)*8;       // over 1024*2048
  unsigned row = idx8 >> 11, c = idx8 & 2047;
  float4 a = *(const float4*)(Wpre + idx8);
  float4 b = *(const float4*)(Wpre + idx8 + 4);
  unsigned short* d = (c < 1024) ? (Bpre + (size_t)row*1536 + c) : (Wc + (size_t)row*1024 + (c-1024));
  *(u16x8*)d = pack8(a,b);
}

// ---------------- root state ----------------
__global__ __launch_bounds__(256) void k_root(const float* __restrict__ rH, const float* __restrict__ rC,
                                              float* __restrict__ Hb, float* __restrict__ Cb,
                                              unsigned short* __restrict__ XH){
  int t = blockIdx.x*256 + threadIdx.x;
  if (t < HD){ Hb[t]=rH[t]; Cb[t]=rC[t]; XH[t]=f2bf(rH[t]); }
}

// ---------------- X assembly: X[slot][j] = [emb(values[p]) | Et_bf[p] | h_bf[p]] ----------------
__global__ __launch_bounds__(256) void k_xasm(const float* __restrict__ emb, const int* __restrict__ values,
                                              const unsigned short* __restrict__ Etb, const unsigned short* __restrict__ XH,
                                              unsigned short* __restrict__ X, int s, int e){
  int i = s + blockIdx.x;
  if (i >= e) return;
  int slot = (i - s) & 3, j = (i - s) >> 2;
  int p = (i - 1) >> 2;
  unsigned short* xr = X + ((size_t)slot*48 + j) * 2560;
  int tid = threadIdx.x;
  if (tid < 64) {                 // wave 0: emb, 512 elems, 8/thread
    int c = tid*8;
    const float* er = emb + (size_t)values[p] * 512;
    float4 a = *(const float4*)(er+c);
    float4 b = *(const float4*)(er+c+4);
    *(u16x8*)(xr+c) = pack8(a,b);
  } else if (tid < 192) {         // waves 1-2: et, 1024 elems, 8/thread
    int c = (tid-64)*8;
    const unsigned short* et = Etb + (size_t)p * 1024;
    *(u16x8*)(xr+512+c) = *(const u16x8*)(et+c);
  } else {                        // wave 3: h, 1024 elems, 16/thread
    int c = (tid-192)*16;
    const unsigned short* hp = XH + (size_t)p * 1536;
    *(u16x8*)(xr+1536+c)   = *(const u16x8*)(hp+c);
    *(u16x8*)(xr+1536+c+8) = *(const u16x8*)(hp+c+8);
  }
}

// ---------------- full-K bf16 GEMM: C[m][n] = A[m]·B[n] + bias[n]; row tile via blockIdx.y ----------------
template<int MT>
__global__ __launch_bounds__(256) void k_gemm_fb(
    const unsigned short* __restrict__ A, int astride,
    const unsigned short* __restrict__ B, int K,
    const float* __restrict__ bias,
    float* __restrict__ Cf, unsigned short* __restrict__ Cb16,
    int ostride, int coff, int N, int M)
{
  const int mb0 = blockIdx.y * (MT*16);
  const int wv = threadIdx.x >> 6, lane = threadIdx.x & 63;
  const int col = (blockIdx.x*4 + wv)*16 + (lane & 15);
  const int colc = min(col, N-1);
  const int khalf = (lane >> 4) * 8;

  f32x4 acc[MT];
  #pragma unroll
  for (int m = 0; m < MT; ++m) acc[m] = (f32x4){0.f,0.f,0.f,0.f};
  int arow[MT];
  #pragma unroll
  for (int m = 0; m < MT; ++m) arow[m] = min(mb0 + m*16 + (lane & 15), M-1);

  #pragma unroll 4
  for (int kk = 0; kk < K; kk += 32) {
    int kb = kk + khalf;
    s16x8 bfv = *(const s16x8*)(B + (size_t)colc*K + kb);
    #pragma unroll
    for (int m = 0; m < MT; ++m) {
      s16x8 af = *(const s16x8*)(A + (size_t)arow[m]*astride + kb);
      acc[m] = MFMA16(af, bfv, acc[m]);
    }
  }

  const int r0 = (lane >> 4) * 4;
  #pragma unroll
  for (int m = 0; m < MT; ++m) {
    #pragma unroll
    for (int q = 0; q < 4; ++q) {
      int row = mb0 + m*16 + r0 + q;
      if (row < M && col < N) {
        float v = acc[m][q] + (bias ? bias[col] : 0.f);
        size_t off = (size_t)row*ostride + col + coff;
        if (Cb16) Cb16[off] = f2bf(v); else Cf[off] = v;
      }
    }
  }
}

// ---------------- split-K + slot-batched bf16 GEMM (LSTM), B split B1|B2: P[((z*KS+ks)*Mpad+row)*N+col] ----------------
template<int MT, int KITER>
__global__ __launch_bounds__(256) void k_gemm_skzb2(
    const unsigned short* __restrict__ A, int astride,
    const unsigned short* __restrict__ B1, int K1,
    const unsigned short* __restrict__ B2, int K2,
    float* __restrict__ P, int N, int Mbase, int Mpad,
    int aZ, int b1Z, int b2Z, int KS)
{
  const int z = blockIdx.z;
  const int M = (Mbase - z + 3) >> 2;
  const unsigned short* Az = A + (size_t)z*aZ;
  const unsigned short* B1z = B1 + (size_t)z*b1Z;
  const unsigned short* B2z = B2 + (size_t)z*b2Z;
  const int ks = blockIdx.y;
  const int k0 = ks * (KITER*32);
  const int wv = threadIdx.x >> 6, lane = threadIdx.x & 63;
  const int col = (blockIdx.x*4 + wv)*16 + (lane & 15);
  const int colc = min(col, N-1);
  const int khalf = (lane >> 4) * 8;

  f32x4 acc[MT];
  #pragma unroll
  for (int m = 0; m < MT; ++m) acc[m] = (f32x4){0.f,0.f,0.f,0.f};
  int arow[MT];
  #pragma unroll
  for (int m = 0; m < MT; ++m) arow[m] = min(m*16 + (lane & 15), M-1);

  #pragma unroll 4
  for (int kk = 0; kk < KITER*32; kk += 32) {
    int kb = k0 + kk + khalf;
    const unsigned short* bp = (kb < K1) ? (B1z + (size_t)colc*K1 + kb)
                                         : (B2z + (size_t)colc*K2 + (kb - K1));
    s16x8 bfv = *(const s16x8*)bp;
    #pragma unroll
    for (int m = 0; m < MT; ++m) {
      s16x8 af = *(const s16x8*)(Az + (size_t)arow[m]*astride + kb);
      acc[m] = MFMA16(af, bfv, acc[m]);
    }
  }

  const int r0 = (lane >> 4) * 4;
  #pragma unroll
  for (int m = 0; m < MT; ++m) {
    #pragma unroll
    for (int q = 0; q < 4; ++q) {
      int row = m*16 + r0 + q;
      if (row < M && col < N)
        P[(((size_t)z*KS + ks)*Mpad + row)*N + col] = acc[m][q];
    }
  }
}

// ---------------- small split-K bf16 GEMM (chunk 128): P[ks][M][N] ----------------
template<int MT>
__global__ __launch_bounds__(256) void k_gemm_skb(
    const unsigned short* __restrict__ A, int astride,
    const unsigned short* __restrict__ B, int K,
    float* __restrict__ P, int N, int M)
{
  const int ks = blockIdx.y;
  const int k0 = ks * 128;
  const int wv = threadIdx.x >> 6, lane = threadIdx.x & 63;
  const int col = (blockIdx.x*4 + wv)*16 + (lane & 15);
  const int colc = min(col, N-1);
  const int khalf = (lane >> 4) * 8;

  f32x4 acc[MT];
  #pragma unroll
  for (int m = 0; m < MT; ++m) acc[m] = (f32x4){0.f,0.f,0.f,0.f};
  int arow[MT];
  #pragma unroll
  for (int m = 0; m < MT; ++m) arow[m] = min(m*16 + (lane & 15), M-1);

  #pragma unroll
  for (int kk = 0; kk < 128; kk += 32) {
    int kb = k0 + kk + khalf;
    s16x8 bfv = *(const s16x8*)(B + (size_t)colc*K + kb);
    #pragma unroll
    for (int m = 0; m < MT; ++m) {
      s16x8 af = *(const s16x8*)(A + (size_t)arow[m]*astride + kb);
      acc[m] = MFMA16(af, bfv, acc[m]);
    }
  }

  const int r0 = (lane >> 4) * 4;
  #pragma unroll
  for (int m = 0; m < MT; ++m) {
    #pragma unroll
    for (int q = 0; q < 4; ++q) {
      int row = m*16 + r0 + q;
      if (row < M && col < N)
        P[((size_t)ks*M + row)*N + col] = acc[m][q];
    }
  }
}

// ---------------- split-K reduction, 4 elems/thread, bf16 out (N mult of 4) ----------------
__global__ __launch_bounds__(256) void k_red4(const float* __restrict__ P, int KS, int M, int N,
                                              const float* __restrict__ bias, int tanh_flag,
                                              unsigned short* __restrict__ Cb16, int ostride)
{
  int idx4 = (blockIdx.x*256 + threadIdx.x)*4;
  if (idx4 >= M*N) return;
  int row = idx4 / N, col = idx4 - row*N;
  float4 s = *(const float4*)(bias + col);
  for (int ks = 0; ks < KS; ++ks) {
    float4 p = *(const float4*)(P + ((size_t)ks*M + row)*N + col);
    s.x += p.x; s.y += p.y; s.z += p.z; s.w += p.w;
  }
  if (tanh_flag){ s.x=tanhfast(s.x); s.y=tanhfast(s.y); s.z=tanhfast(s.z); s.w=tanhfast(s.w); }
  u16x4 r; r[0]=f2bf(s.x); r[1]=f2bf(s.y); r[2]=f2bf(s.z); r[3]=f2bf(s.w);
  *(u16x4*)(Cb16 + (size_t)row*ostride + col) = r;
}

// ---------------- fused split-K sum + softmax over 512 logits -> bf16 probs into XH[.][1024:1536] ----------------
__global__ __launch_bounds__(256) void k_soft(const float* __restrict__ P, int KS, int M,
                                              unsigned short* __restrict__ dst)
{
  __shared__ float sm[512];
  __shared__ float red[8];
  const int m = blockIdx.x;
  const int tid = threadIdx.x, wv = tid>>6, ln = tid&63;
  for (int l = tid; l < 512; l += 256) {
    float s = 0.f;
    for (int ks = 0; ks < KS; ++ks) s += P[((size_t)ks*M + m)*512 + l];
    sm[l] = s;
  }
  __syncthreads();
  float mx = -1e30f;
  for (int l=tid; l<512; l+=256) mx = fmaxf(mx, sm[l]);
  #pragma unroll
  for (int o=32;o;o>>=1) mx = fmaxf(mx, __shfl_xor(mx,o,64));
  if (ln==0) red[wv]=mx;
  __syncthreads();
  mx = fmaxf(fmaxf(red[0],red[1]),fmaxf(red[2],red[3]));
  float se = 0.f;
  for (int l=tid; l<512; l+=256){ float ev=__expf(sm[l]-mx); sm[l]=ev; se+=ev; }
  __syncthreads();
  #pragma unroll
  for (int o=32;o;o>>=1) se += __shfl_xor(se,o,64);
  if (ln==0) red[wv]=se;
  __syncthreads();
  float invS = 1.f/(red[0]+red[1]+red[2]+red[3]);
  for (int l=tid; l<512; l+=256) dst[(size_t)m*1536 + l] = f2bf(sm[l]*invS);
}

// ---------------- LSTM epilogue, vectorized (exactly 256 threads x 4 elems) ----------------
__global__ __launch_bounds__(256) void k_epi(const float* __restrict__ P,
                                             const float* __restrict__ b_ih, const float* __restrict__ b_hh,
                                             float* __restrict__ Hb, float* __restrict__ Cb,
                                             unsigned short* __restrict__ XH, int s, int e){
  int i = s + blockIdx.x;
  if (i >= e) return;
  int slot = (i - s) & 3, j = (i - s) >> 2;
  int p = (i - 1) >> 2;
  const float* bi = b_ih + (size_t)slot*4096;
  const float* bh = b_hh + (size_t)slot*4096;
  const int u = threadIdx.x*4;

  float4 ig, fg, gg, og;
  {
    float4 a, b;
    a = *(const float4*)(bi+u);      b = *(const float4*)(bh+u);      ig = make_float4(a.x+b.x,a.y+b.y,a.z+b.z,a.w+b.w);
    a = *(const float4*)(bi+1024+u); b = *(const float4*)(bh+1024+u); fg = make_float4(a.x+b.x,a.y+b.y,a.z+b.z,a.w+b.w);
    a = *(const float4*)(bi+2048+u); b = *(const float4*)(bh+2048+u); gg = make_float4(a.x+b.x,a.y+b.y,a.z+b.z,a.w+b.w);
    a = *(const float4*)(bi+3072+u); b = *(const float4*)(bh+3072+u); og = make_float4(a.x+b.x,a.y+b.y,a.z+b.z,a.w+b.w);
  }
  #pragma unroll
  for (int ks = 0; ks < 5; ++ks) {
    const float* g = P + (((size_t)slot*5 + ks)*48 + j)*4096;
    float4 a;
    a = *(const float4*)(g+u);      ig.x+=a.x; ig.y+=a.y; ig.z+=a.z; ig.w+=a.w;
    a = *(const float4*)(g+1024+u); fg.x+=a.x; fg.y+=a.y; fg.z+=a.z; fg.w+=a.w;
    a = *(const float4*)(g+2048+u); gg.x+=a.x; gg.y+=a.y; gg.z+=a.z; gg.w+=a.w;
    a = *(const float4*)(g+3072+u); og.x+=a.x; og.y+=a.y; og.z+=a.z; og.w+=a.w;
  }
  float4 cp = *(const float4*)(Cb + (size_t)p*1024 + u);
  float4 cc, hh;
  cc.x = sigf(fg.x)*cp.x + sigf(ig.x)*tanhfast(gg.x); hh.x = sigf(og.x)*tanhfast(cc.x);
  cc.y = sigf(fg.y)*cp.y + sigf(ig.y)*tanhfast(gg.y); hh.y = sigf(og.y)*tanhfast(cc.y);
  cc.z = sigf(fg.z)*cp.z + sigf(ig.z)*tanhfast(gg.z); hh.z = sigf(og.z)*tanhfast(cc.z);
  cc.w = sigf(fg.w)*cp.w + sigf(ig.w)*tanhfast(gg.w); hh.w = sigf(og.w)*tanhfast(cc.w);
  *(float4*)(Hb + (size_t)i*1024 + u) = hh;
  *(float4*)(Cb + (size_t)i*1024 + u) = cc;
  u16x4 r; r[0]=f2bf(hh.x); r[1]=f2bf(hh.y); r[2]=f2bf(hh.z); r[3]=f2bf(hh.w);
  *(u16x4*)(XH + (size_t)i*1536 + u) = r;
}

// ---------------- loss per node (bf16 logits) ----------------
__global__ __launch_bounds__(256) void k_loss(const unsigned short* __restrict__ Lgb,
                                              const int* __restrict__ values,
                                              float* __restrict__ Nl)
{
  __shared__ float red[8];
  const int node = blockIdx.x;
  const int tid = threadIdx.x, wv = tid>>6, ln = tid&63;
  const unsigned short* lg = Lgb + (size_t)node*NCLS;

  float m = -1e30f;
  for (int i=tid;i<NCLS;i+=256) m = fmaxf(m, bf2f(lg[i]));
  #pragma unroll
  for (int o=32;o;o>>=1) m = fmaxf(m, __shfl_xor(m,o,64));
  if (ln==0) red[wv]=m;
  __syncthreads();
  m = fmaxf(fmaxf(red[0],red[1]),fmaxf(red[2],red[3]));
  __syncthreads();

  float s = 0.f;
  for (int i=tid;i<NCLS;i+=256) s += __expf(bf2f(lg[i])-m);
  #pragma unroll
  for (int o=32;o;o>>=1) s += __shfl_xor(s,o,64);
  if (ln==0) red[wv]=s;
  __syncthreads();
  s = red[0]+red[1]+red[2]+red[3];
  __syncthreads();
  float invs = 1.f/s;

  float q = 0.f;
  for (int i=tid;i<NCLS;i+=256) q += __expf(__expf(bf2f(lg[i])-m)*invs);
  #pragma unroll
  for (int o=32;o;o>>=1) q += __shfl_xor(q,o,64);
  if (ln==0) red[wv]=q;
  __syncthreads();
  if (tid==0) {
    float qq = red[0]+red[1]+red[2]+red[3];
    int v = values[node];
    float pv = __expf(bf2f(lg[v])-m)*invs;
    float nl = __logf(qq) - pv;
    if (v == NCLS-1) nl *= 0.2f;
    Nl[node] = nl;
  }
}

__global__ __launch_bounds__(256) void k_final(const float* __restrict__ Nl, float* __restrict__ out){
  __shared__ float red[8];
  int tid = threadIdx.x, wv = tid>>6, ln = tid&63;
  float s = Nl[tid];
  #pragma unroll
  for (int o=32;o;o>>=1) s += __shfl_xor(s,o,64);
  if (ln==0) red[wv]=s;
  __syncthreads();
  if (tid==0) out[0] = red[0]+red[1]+red[2]+red[3];
}

static inline void gemm_skb(hipStream_t st, int MT, const unsigned short* A, int astride,
                            const unsigned short* B, int K, float* P, int N, int M)
{
  dim3 grid(N/64, K/128);
  #define SKCASE(MTv) k_gemm_skb<MTv><<<grid, 256, 0, st>>>(A,astride,B,K,P,N,M)
  switch(MT){
    case 1:  SKCASE(1);  break;
    case 4:  SKCASE(4);  break;
    case 11: SKCASE(11); break;
    default: SKCASE(16); break;
  }
  #undef SKCASE
}

extern "C" void kernel_launch(void* const* d_in, const int* in_sizes, int n_in,
                              void* d_out, int out_size, void* d_ws, size_t ws_size,
                              hipStream_t stream)
{
  const float* rootH = (const float*)d_in[0];
  const float* rootC = (const float*)d_in[1];
  const float* ann   = (const float*)d_in[2];
  const int*   values= (const int*)d_in[3];
  const float* emb   = (const float*)d_in[6];
  const float* W_ih  = (const float*)d_in[7];
  const float* W_hh  = (const float*)d_in[8];
  const float* b_ih  = (const float*)d_in[9];
  const float* b_hh  = (const float*)d_in[10];
  const float* W_att = (const float*)d_in[11];
  const float* b_att = (const float*)d_in[12];
  const float* W_pre = (const float*)d_in[13];
  const float* b_pre = (const float*)d_in[14];
  const float* W_out = (const float*)d_in[15];
  const float* b_out = (const float*)d_in[16];

  float* ws = (float*)d_ws;
  float* Hb  = ws; ws += 256*1024;              // fp32 h
  float* Cb  = ws; ws += 256*1024;              // fp32 c
  float* Nl  = ws; ws += 256;
  float* PB  = ws; ws += 4*5*48*4096;           // shared split-K partials
  unsigned short* Wbih  = (unsigned short*)ws;  // bf16 [4][4096][1536]
  unsigned short* Wbhh  = Wbih  + (size_t)4*4096*1536;   // bf16 [4][4096][1024]
  unsigned short* Woutb = Wbhh  + (size_t)4*4096*1024;   // bf16 [10001][1024]
  unsigned short* Wattb = Woutb + (size_t)NCLS*1024;     // bf16 [1024][1024]
  unsigned short* Bpre  = Wattb + 1024*1024;    // bf16 [1024][1536] = [W_pre_h | ANWT]
  unsigned short* Wpcb  = Bpre  + 1024*1536;    // bf16 [1024][1024] W_pre ctx half
  unsigned short* AHVb  = Wpcb  + 1024*1024;    // bf16 [512][1024]
  unsigned short* Annb  = AHVb  + 512*1024;     // bf16 [512][1024]
  unsigned short* XH    = Annb  + 512*1024;     // bf16 [256][1536] = [h | probs]
  unsigned short* Etb   = XH    + 256*1536;     // bf16 [256][1024]
  unsigned short* Xb    = Etb   + 256*1024;     // bf16 [4][48][2560]
  unsigned short* Lgb   = Xb    + 4*48*2560;    // bf16 [256][10001] logits

  // ---- one-time conversions (pure streams, 32 elems/thread) ----
  k_cvt32 <<<3072, 256, 0, stream>>>(W_ih,  Wbih,  4*4096*1536);
  k_cvt32 <<<2048, 256, 0, stream>>>(W_hh,  Wbhh,  4*4096*1024);
  k_cvt32 <<<1251, 256, 0, stream>>>(W_out, Woutb, NCLS*1024);
  k_cvt32 <<<64,   256, 0, stream>>>(ann,   Annb,  512*1024);
  k_cvt32 <<<128,  256, 0, stream>>>(W_att, Wattb, 1024*1024);
  k_cvtpre8<<<1024, 256, 0, stream>>>(W_pre, Bpre, Wpcb);
  // AHV = ann @ W_att^T + b_att  (bf16 out)
  k_gemm_fb<4><<<dim3(16,8),  256, 0, stream>>>(Annb, 1024, Wattb, 1024, b_att, nullptr, AHVb, 1024, 0, 1024, 512);
  // ANWT[out][l] = W_pre_ctx[out]·ann[l]  -> Bpre[out][1024:1536]
  k_gemm_fb<4><<<dim3(8,16),  256, 0, stream>>>(Wpcb, 1024, Annb, 1024, nullptr, nullptr, Bpre, 1536, 1024, 512, 1024);
  k_root<<<4, 256, 0, stream>>>(rootH, rootC, Hb, Cb, XH);

  const int LS[6] = {0,1,5,21,85,256};
  for (int lev=0; lev<5; ++lev){
    int s=LS[lev], e=LS[lev+1], n=e-s;
    if (lev>0){
      k_xasm<<<n,256,0,stream>>>(emb, values, Etb, XH, Xb, s, e);
      if (lev==4)
        k_gemm_skzb2<3,16><<<dim3(64,5,4),256,0,stream>>>(Xb, 2560, Wbih, 1536, Wbhh, 1024, PB,
            4096, n, 48, 48*2560, 4096*1536, 4096*1024, 5);
      else
        k_gemm_skzb2<1,16><<<dim3(64,5,4),256,0,stream>>>(Xb, 2560, Wbih, 1536, Wbhh, 1024, PB,
            4096, n, 48, 48*2560, 4096*1536, 4096*1024, 5);
      k_epi<<<n,256,0,stream>>>(PB, b_ih, b_hh, Hb, Cb, XH, s, e);
    }
    int mtn = (n+15)/16;
    // attention logits [n x 512] = h · AHV^T (split-K) + fused softmax -> probs into XH[.][1024:1536]
    gemm_skb(stream, mtn, XH + (size_t)s*1536, 1536, AHVb, 1024, PB, 512, n);
    k_soft<<<n,256,0,stream>>>(PB, 8, n, XH + (size_t)s*1536 + 1024);
    // et = tanh([h|probs] · Bpre^T + b_pre)   (ctx GEMM folded into Bpre)
    gemm_skb(stream, mtn, XH + (size_t)s*1536, 1536, Bpre, 1536, PB, 1024, n);
    k_red4<<<(n*1024/4+255)/256, 256, 0, stream>>>(PB, 12, n, 1024, b_pre, 1, Etb + (size_t)s*1024, 1024);
  }

  // W_out logits: full-K bf16, 4 row tiles, bf16 output
  k_gemm_fb<4><<<dim3(157,4), 256, 0, stream>>>(Etb, 1024, Woutb, 1024, b_out, nullptr, Lgb, NCLS, 0, NCLS, 256);
  k_loss <<<256,256,0,stream>>>(Lgb, values, Nl);
  k_final<<<1,  256,0,stream>>>(Nl, (float*)d_out);
}

// Round 10
// 447.406 us; speedup vs baseline: 1.0246x; 1.0246x over previous
//
#include <hip/hip_runtime.h>
#include <hip/hip_bf16.h>
#include <math.h>

#define HD 1024
#define NCLS 10001

typedef short s16x8 __attribute__((ext_vector_type(8)));
typedef unsigned short u16x8 __attribute__((ext_vector_type(8)));
typedef unsigned short u16x4 __attribute__((ext_vector_type(4)));
typedef float f32x4 __attribute__((ext_vector_type(4)));
#define MFMA16(a_, b_, c_) __builtin_amdgcn_mfma_f32_16x16x32_bf16((a_), (b_), (c_), 0, 0, 0)

__device__ __forceinline__ float sigf(float x){ return 1.f/(1.f+__expf(-x)); }
__device__ __forceinline__ float tanhfast(float x){
  x = fminf(fmaxf(x,-10.f),10.f);
  float e2 = __expf(2.f*x);
  return (e2-1.f)/(e2+1.f);
}
__device__ __forceinline__ unsigned short f2bf(float f){
  unsigned int u = __float_as_uint(f);
  u += 0x7FFF + ((u >> 16) & 1);          // round-to-nearest-even
  return (unsigned short)(u >> 16);
}
__device__ __forceinline__ float bf2f(unsigned short u){
  return __uint_as_float(((unsigned)u) << 16);
}
__device__ __forceinline__ u16x8 pack8(float4 a, float4 b){
  u16x8 r;
  r[0]=f2bf(a.x); r[1]=f2bf(a.y); r[2]=f2bf(a.z); r[3]=f2bf(a.w);
  r[4]=f2bf(b.x); r[5]=f2bf(b.y); r[6]=f2bf(b.z); r[7]=f2bf(b.w);
  return r;
}

// ---------------- fp32 -> bf16 bulk convert, 32 elems/thread ----------------
__global__ __launch_bounds__(256) void k_cvt32(const float* __restrict__ A, unsigned short* __restrict__ B, int n){
  int i = (blockIdx.x*256 + threadIdx.x)*32;
  if (i >= n) return;
  float4 a0 = *(const float4*)(A+i+ 0), b0 = *(const float4*)(A+i+ 4);
  float4 a1 = *(const float4*)(A+i+ 8), b1 = *(const float4*)(A+i+12);
  float4 a2 = *(const float4*)(A+i+16), b2 = *(const float4*)(A+i+20);
  float4 a3 = *(const float4*)(A+i+24), b3 = *(const float4*)(A+i+28);
  *(u16x8*)(B+i+ 0) = pack8(a0,b0);
  *(u16x8*)(B+i+ 8) = pack8(a1,b1);
  *(u16x8*)(B+i+16) = pack8(a2,b2);
  *(u16x8*)(B+i+24) = pack8(a3,b3);
}

// ---------------- split W_pre: cols [0,1024) -> Bpre (stride 1536); cols [1024,2048) -> Wc ----------------
__global__ __launch_bounds__(256) void k_cvtpre8(const float* __restrict__ Wpre,
                                                 unsigned short* __restrict__ Bpre, unsigned short* __restrict__ Wc){
  unsigned idx8 = (blockIdx.x*256 + threadIdx.x)*8;       // over 1024*2048
  unsigned row = idx8 >> 11, c = idx8 & 2047;
  float4 a = *(const float4*)(Wpre + idx8);
  float4 b = *(const float4*)(Wpre + idx8 + 4);
  unsigned short* d = (c < 1024) ? (Bpre + (size_t)row*1536 + c) : (Wc + (size_t)row*1024 + (c-1024));
  *(u16x8*)d = pack8(a,b);
}

// ---------------- root state ----------------
__global__ __launch_bounds__(256) void k_root(const float* __restrict__ rH, const float* __restrict__ rC,
                                              float* __restrict__ Hb, float* __restrict__ Cb,
                                              unsigned short* __restrict__ XH){
  int t = blockIdx.x*256 + threadIdx.x;
  if (t < HD){ Hb[t]=rH[t]; Cb[t]=rC[t]; XH[t]=f2bf(rH[t]); }
}

// ---------------- X assembly: X[slot][j] = [emb(values[p]) | Et_bf[p] | h_bf[p]] ----------------
__global__ __launch_bounds__(256) void k_xasm(const float* __restrict__ emb, const int* __restrict__ values,
                                              const unsigned short* __restrict__ Etb, const unsigned short* __restrict__ XH,
                                              unsigned short* __restrict__ X, int s, int e){
  int i = s + blockIdx.x;
  if (i >= e) return;
  int slot = (i - s) & 3, j = (i - s) >> 2;
  int p = (i - 1) >> 2;
  unsigned short* xr = X + ((size_t)slot*48 + j) * 2560;
  int tid = threadIdx.x;
  if (tid < 64) {                 // wave 0: emb, 512 elems, 8/thread
    int c = tid*8;
    const float* er = emb + (size_t)values[p] * 512;
    float4 a = *(const float4*)(er+c);
    float4 b = *(const float4*)(er+c+4);
    *(u16x8*)(xr+c) = pack8(a,b);
  } else if (tid < 192) {         // waves 1-2: et, 1024 elems, 8/thread
    int c = (tid-64)*8;
    const unsigned short* et = Etb + (size_t)p * 1024;
    *(u16x8*)(xr+512+c) = *(const u16x8*)(et+c);
  } else {                        // wave 3: h, 1024 elems, 16/thread
    int c = (tid-192)*16;
    const unsigned short* hp = XH + (size_t)p * 1536;
    *(u16x8*)(xr+1536+c)   = *(const u16x8*)(hp+c);
    *(u16x8*)(xr+1536+c+8) = *(const u16x8*)(hp+c+8);
  }
}

// ---------------- full-K bf16 GEMM (AHV / ANWT prep) ----------------
template<int MT>
__global__ __launch_bounds__(256) void k_gemm_fb(
    const unsigned short* __restrict__ A, int astride,
    const unsigned short* __restrict__ B, int K,
    const float* __restrict__ bias,
    float* __restrict__ Cf, unsigned short* __restrict__ Cb16,
    int ostride, int coff, int N, int M)
{
  const int mb0 = blockIdx.y * (MT*16);
  const int wv = threadIdx.x >> 6, lane = threadIdx.x & 63;
  const int col = (blockIdx.x*4 + wv)*16 + (lane & 15);
  const int colc = min(col, N-1);
  const int khalf = (lane >> 4) * 8;

  f32x4 acc[MT];
  #pragma unroll
  for (int m = 0; m < MT; ++m) acc[m] = (f32x4){0.f,0.f,0.f,0.f};
  int arow[MT];
  #pragma unroll
  for (int m = 0; m < MT; ++m) arow[m] = min(mb0 + m*16 + (lane & 15), M-1);

  #pragma unroll 4
  for (int kk = 0; kk < K; kk += 32) {
    int kb = kk + khalf;
    s16x8 bfv = *(const s16x8*)(B + (size_t)colc*K + kb);
    #pragma unroll
    for (int m = 0; m < MT; ++m) {
      s16x8 af = *(const s16x8*)(A + (size_t)arow[m]*astride + kb);
      acc[m] = MFMA16(af, bfv, acc[m]);
    }
  }

  const int r0 = (lane >> 4) * 4;
  #pragma unroll
  for (int m = 0; m < MT; ++m) {
    #pragma unroll
    for (int q = 0; q < 4; ++q) {
      int row = mb0 + m*16 + r0 + q;
      if (row < M && col < N) {
        float v = acc[m][q] + (bias ? bias[col] : 0.f);
        size_t off = (size_t)row*ostride + col + coff;
        if (Cb16) Cb16[off] = f2bf(v); else Cf[off] = v;
      }
    }
  }
}

// ---------------- W_out GEMM with LDS-staged B: block = 16 cols, 4 waves x 64-row tiles ----------------
// B rows for 16 consecutive cols are 32KB contiguous; staged to LDS (row pad +8 elems -> 2-way bank alias only).
__global__ __launch_bounds__(256) void k_wout(
    const unsigned short* __restrict__ A,      // Etb [256][1024]
    const unsigned short* __restrict__ B,      // Woutb [10001][1024] (+ slack after)
    const float* __restrict__ bias,
    unsigned short* __restrict__ Lgb)
{
  __shared__ unsigned short bs[16*1032];
  const int c0 = blockIdx.x*16;
  const int tid = threadIdx.x;
  const unsigned short* src = B + (size_t)c0*1024;
  #pragma unroll
  for (int it = 0; it < 8; ++it) {
    int e = it*2048 + tid*8;
    int row = e >> 10, ck = e & 1023;
    *(u16x8*)(bs + row*1032 + ck) = *(const u16x8*)(src + e);
  }
  __syncthreads();

  const int wv = tid >> 6, lane = tid & 63;
  const int col16 = lane & 15;
  const int khalf = (lane >> 4) * 8;
  const int mb0 = wv * 64;
  const int col = c0 + col16;

  f32x4 acc[4];
  #pragma unroll
  for (int m=0;m<4;++m) acc[m] = (f32x4){0.f,0.f,0.f,0.f};
  int arow[4];
  #pragma unroll
  for (int m=0;m<4;++m) arow[m] = mb0 + m*16 + col16;

  #pragma unroll 8
  for (int kk = 0; kk < 1024; kk += 32) {
    int kb = kk + khalf;
    s16x8 bfv = *(const s16x8*)(bs + col16*1032 + kb);
    #pragma unroll
    for (int m=0;m<4;++m) {
      s16x8 af = *(const s16x8*)(A + (size_t)arow[m]*1024 + kb);
      acc[m] = MFMA16(af, bfv, acc[m]);
    }
  }

  if (col < NCLS) {
    const int r0 = (lane >> 4) * 4;
    float bv = bias[col];
    #pragma unroll
    for (int m=0;m<4;++m) {
      #pragma unroll
      for (int q=0;q<4;++q) {
        int row = mb0 + m*16 + r0 + q;
        Lgb[(size_t)row*NCLS + col] = f2bf(acc[m][q] + bv);
      }
    }
  }
}

// ---------------- split-K + slot-batched bf16 GEMM (LSTM), B split B1|B2 ----------------
template<int MT, int KITER>
__global__ __launch_bounds__(256) void k_gemm_skzb2(
    const unsigned short* __restrict__ A, int astride,
    const unsigned short* __restrict__ B1, int K1,
    const unsigned short* __restrict__ B2, int K2,
    float* __restrict__ P, int N, int Mbase, int Mpad,
    int aZ, int b1Z, int b2Z, int KS)
{
  const int z = blockIdx.z;
  const int M = (Mbase - z + 3) >> 2;
  const unsigned short* Az = A + (size_t)z*aZ;
  const unsigned short* B1z = B1 + (size_t)z*b1Z;
  const unsigned short* B2z = B2 + (size_t)z*b2Z;
  const int ks = blockIdx.y;
  const int k0 = ks * (KITER*32);
  const int wv = threadIdx.x >> 6, lane = threadIdx.x & 63;
  const int col = (blockIdx.x*4 + wv)*16 + (lane & 15);
  const int colc = min(col, N-1);
  const int khalf = (lane >> 4) * 8;

  f32x4 acc[MT];
  #pragma unroll
  for (int m = 0; m < MT; ++m) acc[m] = (f32x4){0.f,0.f,0.f,0.f};
  int arow[MT];
  #pragma unroll
  for (int m = 0; m < MT; ++m) arow[m] = min(m*16 + (lane & 15), M-1);

  #pragma unroll 8
  for (int kk = 0; kk < KITER*32; kk += 32) {
    int kb = k0 + kk + khalf;
    const unsigned short* bp = (kb < K1) ? (B1z + (size_t)colc*K1 + kb)
                                         : (B2z + (size_t)colc*K2 + (kb - K1));
    s16x8 bfv = *(const s16x8*)bp;
    #pragma unroll
    for (int m = 0; m < MT; ++m) {
      s16x8 af = *(const s16x8*)(Az + (size_t)arow[m]*astride + kb);
      acc[m] = MFMA16(af, bfv, acc[m]);
    }
  }

  const int r0 = (lane >> 4) * 4;
  #pragma unroll
  for (int m = 0; m < MT; ++m) {
    #pragma unroll
    for (int q = 0; q < 4; ++q) {
      int row = m*16 + r0 + q;
      if (row < M && col < N)
        P[(((size_t)z*KS + ks)*Mpad + row)*N + col] = acc[m][q];
    }
  }
}

// ---------------- small split-K bf16 GEMM (chunk 128): P[ks][M][N] ----------------
template<int MT>
__global__ __launch_bounds__(256) void k_gemm_skb(
    const unsigned short* __restrict__ A, int astride,
    const unsigned short* __restrict__ B, int K,
    float* __restrict__ P, int N, int M)
{
  const int ks = blockIdx.y;
  const int k0 = ks * 128;
  const int wv = threadIdx.x >> 6, lane = threadIdx.x & 63;
  const int col = (blockIdx.x*4 + wv)*16 + (lane & 15);
  const int colc = min(col, N-1);
  const int khalf = (lane >> 4) * 8;

  f32x4 acc[MT];
  #pragma unroll
  for (int m = 0; m < MT; ++m) acc[m] = (f32x4){0.f,0.f,0.f,0.f};
  int arow[MT];
  #pragma unroll
  for (int m = 0; m < MT; ++m) arow[m] = min(m*16 + (lane & 15), M-1);

  #pragma unroll
  for (int kk = 0; kk < 128; kk += 32) {
    int kb = k0 + kk + khalf;
    s16x8 bfv = *(const s16x8*)(B + (size_t)colc*K + kb);
    #pragma unroll
    for (int m = 0; m < MT; ++m) {
      s16x8 af = *(const s16x8*)(A + (size_t)arow[m]*astride + kb);
      acc[m] = MFMA16(af, bfv, acc[m]);
    }
  }

  const int r0 = (lane >> 4) * 4;
  #pragma unroll
  for (int m = 0; m < MT; ++m) {
    #pragma unroll
    for (int q = 0; q < 4; ++q) {
      int row = m*16 + r0 + q;
      if (row < M && col < N)
        P[((size_t)ks*M + row)*N + col] = acc[m][q];
    }
  }
}

// ---------------- split-K reduction, 4 elems/thread, bf16 out ----------------
__global__ __launch_bounds__(256) void k_red4(const float* __restrict__ P, int KS, int M, int N,
                                              const float* __restrict__ bias, int tanh_flag,
                                              unsigned short* __restrict__ Cb16, int ostride)
{
  int idx4 = (blockIdx.x*256 + threadIdx.x)*4;
  if (idx4 >= M*N) return;
  int row = idx4 / N, col = idx4 - row*N;
  float4 s = *(const float4*)(bias + col);
  for (int ks = 0; ks < KS; ++ks) {
    float4 p = *(const float4*)(P + ((size_t)ks*M + row)*N + col);
    s.x += p.x; s.y += p.y; s.z += p.z; s.w += p.w;
  }
  if (tanh_flag){ s.x=tanhfast(s.x); s.y=tanhfast(s.y); s.z=tanhfast(s.z); s.w=tanhfast(s.w); }
  u16x4 r; r[0]=f2bf(s.x); r[1]=f2bf(s.y); r[2]=f2bf(s.z); r[3]=f2bf(s.w);
  *(u16x4*)(Cb16 + (size_t)row*ostride + col) = r;
}

// ---------------- fused split-K sum + softmax over 512 logits -> bf16 probs into XH[.][1024:1536] ----------------
__global__ __launch_bounds__(256) void k_soft(const float* __restrict__ P, int KS, int M,
                                              unsigned short* __restrict__ dst)
{
  __shared__ float sm[512];
  __shared__ float red[8];
  const int m = blockIdx.x;
  const int tid = threadIdx.x, wv = tid>>6, ln = tid&63;
  for (int l = tid; l < 512; l += 256) {
    float s = 0.f;
    for (int ks = 0; ks < KS; ++ks) s += P[((size_t)ks*M + m)*512 + l];
    sm[l] = s;
  }
  __syncthreads();
  float mx = -1e30f;
  for (int l=tid; l<512; l+=256) mx = fmaxf(mx, sm[l]);
  #pragma unroll
  for (int o=32;o;o>>=1) mx = fmaxf(mx, __shfl_xor(mx,o,64));
  if (ln==0) red[wv]=mx;
  __syncthreads();
  mx = fmaxf(fmaxf(red[0],red[1]),fmaxf(red[2],red[3]));
  float se = 0.f;
  for (int l=tid; l<512; l+=256){ float ev=__expf(sm[l]-mx); sm[l]=ev; se+=ev; }
  __syncthreads();
  #pragma unroll
  for (int o=32;o;o>>=1) se += __shfl_xor(se,o,64);
  if (ln==0) red[wv]=se;
  __syncthreads();
  float invS = 1.f/(red[0]+red[1]+red[2]+red[3]);
  for (int l=tid; l<512; l+=256) dst[(size_t)m*1536 + l] = f2bf(sm[l]*invS);
}

// ---------------- LSTM epilogue, vectorized ----------------
__global__ __launch_bounds__(256) void k_epi(const float* __restrict__ P,
                                             const float* __restrict__ b_ih, const float* __restrict__ b_hh,
                                             float* __restrict__ Hb, float* __restrict__ Cb,
                                             unsigned short* __restrict__ XH, int s, int e){
  int i = s + blockIdx.x;
  if (i >= e) return;
  int slot = (i - s) & 3, j = (i - s) >> 2;
  int p = (i - 1) >> 2;
  const float* bi = b_ih + (size_t)slot*4096;
  const float* bh = b_hh + (size_t)slot*4096;
  const int u = threadIdx.x*4;

  float4 ig, fg, gg, og;
  {
    float4 a, b;
    a = *(const float4*)(bi+u);      b = *(const float4*)(bh+u);      ig = make_float4(a.x+b.x,a.y+b.y,a.z+b.z,a.w+b.w);
    a = *(const float4*)(bi+1024+u); b = *(const float4*)(bh+1024+u); fg = make_float4(a.x+b.x,a.y+b.y,a.z+b.z,a.w+b.w);
    a = *(const float4*)(bi+2048+u); b = *(const float4*)(bh+2048+u); gg = make_float4(a.x+b.x,a.y+b.y,a.z+b.z,a.w+b.w);
    a = *(const float4*)(bi+3072+u); b = *(const float4*)(bh+3072+u); og = make_float4(a.x+b.x,a.y+b.y,a.z+b.z,a.w+b.w);
  }
  #pragma unroll
  for (int ks = 0; ks < 5; ++ks) {
    const float* g = P + (((size_t)slot*5 + ks)*48 + j)*4096;
    float4 a;
    a = *(const float4*)(g+u);      ig.x+=a.x; ig.y+=a.y; ig.z+=a.z; ig.w+=a.w;
    a = *(const float4*)(g+1024+u); fg.x+=a.x; fg.y+=a.y; fg.z+=a.z; fg.w+=a.w;
    a = *(const float4*)(g+2048+u); gg.x+=a.x; gg.y+=a.y; gg.z+=a.z; gg.w+=a.w;
    a = *(const float4*)(g+3072+u); og.x+=a.x; og.y+=a.y; og.z+=a.z; og.w+=a.w;
  }
  float4 cp = *(const float4*)(Cb + (size_t)p*1024 + u);
  float4 cc, hh;
  cc.x = sigf(fg.x)*cp.x + sigf(ig.x)*tanhfast(gg.x); hh.x = sigf(og.x)*tanhfast(cc.x);
  cc.y = sigf(fg.y)*cp.y + sigf(ig.y)*tanhfast(gg.y); hh.y = sigf(og.y)*tanhfast(cc.y);
  cc.z = sigf(fg.z)*cp.z + sigf(ig.z)*tanhfast(gg.z); hh.z = sigf(og.z)*tanhfast(cc.z);
  cc.w = sigf(fg.w)*cp.w + sigf(ig.w)*tanhfast(gg.w); hh.w = sigf(og.w)*tanhfast(cc.w);
  *(float4*)(Hb + (size_t)i*1024 + u) = hh;
  *(float4*)(Cb + (size_t)i*1024 + u) = cc;
  u16x4 r; r[0]=f2bf(hh.x); r[1]=f2bf(hh.y); r[2]=f2bf(hh.z); r[3]=f2bf(hh.w);
  *(u16x4*)(XH + (size_t)i*1536 + u) = r;
}

// ---------------- loss per node (bf16 logits) ----------------
__global__ __launch_bounds__(256) void k_loss(const unsigned short* __restrict__ Lgb,
                                              const int* __restrict__ values,
                                              float* __restrict__ Nl)
{
  __shared__ float red[8];
  const int node = blockIdx.x;
  const int tid = threadIdx.x, wv = tid>>6, ln = tid&63;
  const unsigned short* lg = Lgb + (size_t)node*NCLS;

  float m = -1e30f;
  for (int i=tid;i<NCLS;i+=256) m = fmaxf(m, bf2f(lg[i]));
  #pragma unroll
  for (int o=32;o;o>>=1) m = fmaxf(m, __shfl_xor(m,o,64));
  if (ln==0) red[wv]=m;
  __syncthreads();
  m = fmaxf(fmaxf(red[0],red[1]),fmaxf(red[2],red[3]));
  __syncthreads();

  float s = 0.f;
  for (int i=tid;i<NCLS;i+=256) s += __expf(bf2f(lg[i])-m);
  #pragma unroll
  for (int o=32;o;o>>=1) s += __shfl_xor(s,o,64);
  if (ln==0) red[wv]=s;
  __syncthreads();
  s = red[0]+red[1]+red[2]+red[3];
  __syncthreads();
  float invs = 1.f/s;

  float q = 0.f;
  for (int i=tid;i<NCLS;i+=256) q += __expf(__expf(bf2f(lg[i])-m)*invs);
  #pragma unroll
  for (int o=32;o;o>>=1) q += __shfl_xor(q,o,64);
  if (ln==0) red[wv]=q;
  __syncthreads();
  if (tid==0) {
    float qq = red[0]+red[1]+red[2]+red[3];
    int v = values[node];
    float pv = __expf(bf2f(lg[v])-m)*invs;
    float nl = __logf(qq) - pv;
    if (v == NCLS-1) nl *= 0.2f;
    Nl[node] = nl;
  }
}

__global__ __launch_bounds__(256) void k_final(const float* __restrict__ Nl, float* __restrict__ out){
  __shared__ float red[8];
  int tid = threadIdx.x, wv = tid>>6, ln = tid&63;
  float s = Nl[tid];
  #pragma unroll
  for (int o=32;o;o>>=1) s += __shfl_xor(s,o,64);
  if (ln==0) red[wv]=s;
  __syncthreads();
  if (tid==0) out[0] = red[0]+red[1]+red[2]+red[3];
}

static inline void gemm_skb(hipStream_t st, int MT, const unsigned short* A, int astride,
                            const unsigned short* B, int K, float* P, int N, int M)
{
  dim3 grid(N/64, K/128);
  #define SKCASE(MTv) k_gemm_skb<MTv><<<grid, 256, 0, st>>>(A,astride,B,K,P,N,M)
  switch(MT){
    case 1:  SKCASE(1);  break;
    case 4:  SKCASE(4);  break;
    case 11: SKCASE(11); break;
    default: SKCASE(16); break;
  }
  #undef SKCASE
}

extern "C" void kernel_launch(void* const* d_in, const int* in_sizes, int n_in,
                              void* d_out, int out_size, void* d_ws, size_t ws_size,
                              hipStream_t stream)
{
  const float* rootH = (const float*)d_in[0];
  const float* rootC = (const float*)d_in[1];
  const float* ann   = (const float*)d_in[2];
  const int*   values= (const int*)d_in[3];
  const float* emb   = (const float*)d_in[6];
  const float* W_ih  = (const float*)d_in[7];
  const float* W_hh  = (const float*)d_in[8];
  const float* b_ih  = (const float*)d_in[9];
  const float* b_hh  = (const float*)d_in[10];
  const float* W_att = (const float*)d_in[11];
  const float* b_att = (const float*)d_in[12];
  const float* W_pre = (const float*)d_in[13];
  const float* b_pre = (const float*)d_in[14];
  const float* W_out = (const float*)d_in[15];
  const float* b_out = (const float*)d_in[16];

  float* ws = (float*)d_ws;
  float* Hb  = ws; ws += 256*1024;              // fp32 h
  float* Cb  = ws; ws += 256*1024;              // fp32 c
  float* Nl  = ws; ws += 256;
  float* PB  = ws; ws += 4*5*48*4096;           // shared split-K partials
  unsigned short* Wbih  = (unsigned short*)ws;  // bf16 [4][4096][1536]
  unsigned short* Wbhh  = Wbih  + (size_t)4*4096*1536;   // bf16 [4][4096][1024]
  unsigned short* Woutb = Wbhh  + (size_t)4*4096*1024;   // bf16 [10001][1024]
  unsigned short* Wattb = Woutb + (size_t)NCLS*1024;     // bf16 [1024][1024] (doubles as k_wout OOB slack)
  unsigned short* Bpre  = Wattb + 1024*1024;    // bf16 [1024][1536] = [W_pre_h | ANWT]
  unsigned short* Wpcb  = Bpre  + 1024*1536;    // bf16 [1024][1024] W_pre ctx half
  unsigned short* AHVb  = Wpcb  + 1024*1024;    // bf16 [512][1024]
  unsigned short* Annb  = AHVb  + 512*1024;     // bf16 [512][1024]
  unsigned short* XH    = Annb  + 512*1024;     // bf16 [256][1536] = [h | probs]
  unsigned short* Etb   = XH    + 256*1536;     // bf16 [256][1024]
  unsigned short* Xb    = Etb   + 256*1024;     // bf16 [4][48][2560]
  unsigned short* Lgb   = Xb    + 4*48*2560;    // bf16 [256][10001] logits

  // ---- one-time conversions (pure streams, 32 elems/thread) ----
  k_cvt32 <<<3072, 256, 0, stream>>>(W_ih,  Wbih,  4*4096*1536);
  k_cvt32 <<<2048, 256, 0, stream>>>(W_hh,  Wbhh,  4*4096*1024);
  k_cvt32 <<<1251, 256, 0, stream>>>(W_out, Woutb, NCLS*1024);
  k_cvt32 <<<64,   256, 0, stream>>>(ann,   Annb,  512*1024);
  k_cvt32 <<<128,  256, 0, stream>>>(W_att, Wattb, 1024*1024);
  k_cvtpre8<<<1024, 256, 0, stream>>>(W_pre, Bpre, Wpcb);
  // AHV = ann @ W_att^T + b_att  (bf16 out)
  k_gemm_fb<4><<<dim3(16,8),  256, 0, stream>>>(Annb, 1024, Wattb, 1024, b_att, nullptr, AHVb, 1024, 0, 1024, 512);
  // ANWT[out][l] = W_pre_ctx[out]·ann[l]  -> Bpre[out][1024:1536]
  k_gemm_fb<4><<<dim3(8,16),  256, 0, stream>>>(Wpcb, 1024, Annb, 1024, nullptr, nullptr, Bpre, 1536, 1024, 512, 1024);
  k_root<<<4, 256, 0, stream>>>(rootH, rootC, Hb, Cb, XH);

  const int LS[6] = {0,1,5,21,85,256};
  for (int lev=0; lev<5; ++lev){
    int s=LS[lev], e=LS[lev+1], n=e-s;
    if (lev>0){
      k_xasm<<<n,256,0,stream>>>(emb, values, Etb, XH, Xb, s, e);
      if (lev==4)
        k_gemm_skzb2<3,16><<<dim3(64,5,4),256,0,stream>>>(Xb, 2560, Wbih, 1536, Wbhh, 1024, PB,
            4096, n, 48, 48*2560, 4096*1536, 4096*1024, 5);
      else
        k_gemm_skzb2<1,16><<<dim3(64,5,4),256,0,stream>>>(Xb, 2560, Wbih, 1536, Wbhh, 1024, PB,
            4096, n, 48, 48*2560, 4096*1536, 4096*1024, 5);
      k_epi<<<n,256,0,stream>>>(PB, b_ih, b_hh, Hb, Cb, XH, s, e);
    }
    int mtn = (n+15)/16;
    // attention logits [n x 512] = h · AHV^T (split-K) + fused softmax -> probs into XH[.][1024:1536]
    gemm_skb(stream, mtn, XH + (size_t)s*1536, 1536, AHVb, 1024, PB, 512, n);
    k_soft<<<n,256,0,stream>>>(PB, 8, n, XH + (size_t)s*1536 + 1024);
    // et = tanh([h|probs] · Bpre^T + b_pre)   (ctx GEMM folded into Bpre)
    gemm_skb(stream, mtn, XH + (size_t)s*1536, 1536, Bpre, 1536, PB, 1024, n);
    k_red4<<<(n*1024/4+255)/256, 256, 0, stream>>>(PB, 12, n, 1024, b_pre, 1, Etb + (size_t)s*1024, 1024);
  }

  // W_out logits: LDS-staged B, 626 blocks (16 cols each), bf16 output
  k_wout<<<626, 256, 0, stream>>>(Etb, Woutb, b_out, Lgb);
  k_loss <<<256,256,0,stream>>>(Lgb, values, Nl);
  k_final<<<1,  256,0,stream>>>(Nl, (float*)d_out);
}